// Round 9
// baseline (144.539 us; speedup 1.0000x reference)
//
#include <hip/hip_runtime.h>

#define NODE_DIM 128
#define EDGE_DIM 16
#define MSG_DIM 128
#define HID 256
#define NB 8
#define NN 256

typedef short bf16x8 __attribute__((ext_vector_type(8)));
typedef float f32x4 __attribute__((ext_vector_type(4)));

__device__ __forceinline__ unsigned short f2bf(float f) {
  unsigned u = __float_as_uint(f);
  return (unsigned short)((u + 0x7FFF + ((u >> 16) & 1)) >> 16);
}
__device__ __forceinline__ unsigned pack_bf2(float lo, float hi) {
  unsigned a = __float_as_uint(lo), b = __float_as_uint(hi);
  a = (a + 0x7FFF + ((a >> 16) & 1)) >> 16;
  b = (b + 0x7FFF + ((b >> 16) & 1)) & 0xFFFF0000u;
  return a | b;
}

union BF8 { bf16x8 v; unsigned u[4]; unsigned short s[8]; };

__device__ __forceinline__ BF8 make_bf8(float4 a, float4 b) {
  BF8 r;
  r.u[0] = pack_bf2(a.x, a.y); r.u[1] = pack_bf2(a.z, a.w);
  r.u[2] = pack_bf2(b.x, b.y); r.u[3] = pack_bf2(b.z, b.w);
  return r;
}

// Packed-fragment sizes (shorts). Frag (nt,ks): 64 lanes x 8 bf16 (16B/lane).
// PW1: nt 0..15, ks 0..8 (rows 0..287, zero-padded past 272; ks=8 = the edge
// rows 256..271 + pad -> exactly k2's B-fragment). Others: ks 0..7.
#define PW1_SHORTS (16 * 9 * 64 * 8)
#define PW2_SHORTS (8 * 8 * 64 * 8)
#define PU1_SHORTS (16 * 8 * 64 * 8)
#define PU2_SHORTS (8 * 8 * 64 * 8)

// ---------------------------------------------------------------------------
// kW: repack W1/W2/U1/U2 fp32 -> bf16 B-fragment order.
// ---------------------------------------------------------------------------
__global__ __launch_bounds__(256) void kw_pack(
    const float* __restrict__ W1, const float* __restrict__ W2,
    const float* __restrict__ U1, const float* __restrict__ U2,
    unsigned short* __restrict__ P) {
  const int gl = blockIdx.x * 256 + threadIdx.x;
  const float* W; unsigned short* dst; int nt, ks, lane, N, K;
  int i = gl;
  if (i < 16 * 9 * 64) {
    W = W1; dst = P; nt = i / (9 * 64); ks = (i / 64) % 9; lane = i & 63;
    N = HID; K = 272;
  } else if ((i -= 16 * 9 * 64) < 8 * 8 * 64) {
    W = W2; dst = P + PW1_SHORTS; nt = i / (8 * 64); ks = (i / 64) % 8;
    lane = i & 63; N = MSG_DIM; K = 256;
  } else if ((i -= 8 * 8 * 64) < 16 * 8 * 64) {
    W = U1; dst = P + PW1_SHORTS + PW2_SHORTS; nt = i / (8 * 64);
    ks = (i / 64) % 8; lane = i & 63; N = HID; K = 256;
  } else if ((i -= 16 * 8 * 64) < 8 * 8 * 64) {
    W = U2; dst = P + PW1_SHORTS + PW2_SHORTS + PU1_SHORTS; nt = i / (8 * 64);
    ks = (i / 64) % 8; lane = i & 63; N = NODE_DIM; K = 256;
  } else {
    return;
  }
  const int quad = lane >> 4, ln = lane & 15;
  float v[8];
#pragma unroll
  for (int j = 0; j < 8; j++) {
    const int row = ks * 32 + quad * 8 + j;
    v[j] = (row < K) ? W[(size_t)row * N + nt * 16 + ln] : 0.f;
  }
  BF8 r;
#pragma unroll
  for (int t = 0; t < 4; t++) r.u[t] = pack_bf2(v[2 * t], v[2 * t + 1]);
  *(BF8*)(dst + (size_t)((nt * ((W == W1) ? 9 : 8) + ks) * 64 + lane) * 8) = r;
}

// ---------------------------------------------------------------------------
// K1 (MFMA, no barriers, packed B): Ha = h@W1[0:128]+b1 (row-major);
// HbT[b][c][j] = (h@W1[128:256])^T (transposed for k2's register loads).
// Grid 256 = 128 rowBlks x 2 col-halves; wave -> 2 n-tiles.
// ---------------------------------------------------------------------------
__global__ __launch_bounds__(256) void k1_mfma(
    const float* __restrict__ h, const unsigned short* __restrict__ PW1,
    const float* __restrict__ b1, float* __restrict__ Ha, float* __restrict__ HbT) {
  const int tid = threadIdx.x;
  const int lane = tid & 63;
  const int wave = tid >> 6;
  const int ln = lane & 15;
  const int quad = lane >> 4;
  const int r0 = (blockIdx.x >> 1) * 16;
  const int nbase = (blockIdx.x & 1) * 8;
  const int b = r0 >> 8;
  const int jloc = r0 & 255;

  BF8 afr[4];
  const float4* h4 = (const float4*)h;
  const int abase = (r0 + ln) * 32 + quad * 2;
#pragma unroll
  for (int ks = 0; ks < 4; ks++)
    afr[ks] = make_bf8(h4[abase + ks * 8], h4[abase + ks * 8 + 1]);

#pragma unroll
  for (int t = 0; t < 2; t++) {
    const int nt = nbase + wave * 2 + t;  // 0..15
    const int ncol = nt * 16 + ln;
    const float seed = b1[ncol];
    f32x4 acc_a, acc_b;
    acc_a[0] = seed; acc_a[1] = seed; acc_a[2] = seed; acc_a[3] = seed;
    acc_b[0] = 0.f; acc_b[1] = 0.f; acc_b[2] = 0.f; acc_b[3] = 0.f;
#pragma unroll
    for (int ks = 0; ks < 4; ks++) {
      const BF8 bfa = *(const BF8*)(PW1 + (size_t)((nt * 9 + ks) * 64 + lane) * 8);
      const BF8 bfb = *(const BF8*)(PW1 + (size_t)((nt * 9 + ks + 4) * 64 + lane) * 8);
      acc_a = __builtin_amdgcn_mfma_f32_16x16x32_bf16(afr[ks].v, bfa.v, acc_a, 0, 0, 0);
      acc_b = __builtin_amdgcn_mfma_f32_16x16x32_bf16(afr[ks].v, bfb.v, acc_b, 0, 0, 0);
    }
#pragma unroll
    for (int r = 0; r < 4; r++) {
      Ha[(size_t)(r0 + quad * 4 + r) * HID + ncol] = acc_a[r];
      // transposed: HbT[((b*256 + ncol))*256 + j]; 4 r-stores fill 16B runs
      HbT[((size_t)(b * 256) + ncol) * 256 + jloc + quad * 4 + r] = acc_b[r];
    }
  }
}

// ---------------------------------------------------------------------------
// K2 v2 (MFMA, ONE barrier): per block 4 i-rows (same batch b).
//   aggH[i,c] = sum_j adj[i,j]*relu(Ha[i,c] + Hb[j,c] + E[i,j,:]@W1c[:,c])
// j-loop is barrier-free: Hb comes from HbT via one dwordx4 per (jt,ct)
// (lane reads HbT[colb][j0+quad*4 .. +3] = its 4 C-rows); E/adj staged in
// LDS once. MFMA C seeded per-row with ha+hb (exact fp32 add in MFMA).
// B-fragment = PW1 ks=8 (edge rows, zero-padded K 16->32).
// ---------------------------------------------------------------------------
__global__ __launch_bounds__(256) void k2_mfma(
    const float* __restrict__ Ha, const float* __restrict__ HbT,
    const float* __restrict__ E, const float* __restrict__ adj,
    const unsigned short* __restrict__ PW1, float* __restrict__ aggH,
    float* __restrict__ cnt) {
  __shared__ __align__(16) unsigned sEbU[4 * NN * 12];  // 48 KB bf16 E, stride 12 u32
  __shared__ __align__(16) float sAdj[4 * NN];          // 4 KB
  const int tid = threadIdx.x;
  const int lane = tid & 63;
  const int wave = tid >> 6;
  const int n = lane & 15;
  const int quad = lane >> 4;
  const int c0 = wave * 64;
  const int r0 = blockIdx.x * 4;
  const int b = r0 >> 8;

  // ---- stage E (fp32 -> bf16) and adj ----
  const float4* Eb4 = (const float4*)(E + (size_t)r0 * NN * EDGE_DIM);
  for (int q = tid; q < 4 * NN * 4; q += 256) {
    const float4 v = Eb4[q];
    const int row = q >> 2;
    const int ku = (q & 3) << 1;
    sEbU[row * 12 + ku] = pack_bf2(v.x, v.y);
    sEbU[row * 12 + ku + 1] = pack_bf2(v.z, v.w);
  }
  for (int idx = tid; idx < 4 * NN; idx += 256)
    sAdj[idx] = adj[(size_t)r0 * NN + idx];

  // ---- B fragments from packed W1 (ks=8 = edge rows + pad) ----
  BF8 bfrag[4];
#pragma unroll
  for (int ct = 0; ct < 4; ct++) {
    const int nt = (c0 >> 4) + ct;
    bfrag[ct] = *(const BF8*)(PW1 + (size_t)((nt * 9 + 8) * 64 + lane) * 8);
  }
  // ---- Ha values (col depends only on lane&15) ----
  float hav[4][4];
#pragma unroll
  for (int i = 0; i < 4; i++)
#pragma unroll
    for (int ct = 0; ct < 4; ct++)
      hav[i][ct] = Ha[(size_t)(r0 + i) * HID + c0 + ct * 16 + n];

  __syncthreads();  // the only barrier

  // ---- cnt: wave w reduces sAdj row w ----
  {
    float s = sAdj[wave * NN + lane] + sAdj[wave * NN + lane + 64] +
              sAdj[wave * NN + lane + 128] + sAdj[wave * NN + lane + 192];
    for (int d = 32; d; d >>= 1) s += __shfl_xor(s, d);
    if (lane == 0) cnt[r0 + wave] = s;
  }

  float outp[4][4];
#pragma unroll
  for (int i = 0; i < 4; i++)
#pragma unroll
    for (int ct = 0; ct < 4; ct++) outp[i][ct] = 0.f;

  // ---- barrier-free main loop over j-tiles of 16 ----
  for (int jt = 0; jt < 16; jt++) {
    const int j0 = jt * 16;
    // this lane's 4 Hb values per c-tile: HbT[b][colb][j0+quad*4 .. +3]
    float4 hbv[4];
#pragma unroll
    for (int ct = 0; ct < 4; ct++)
      hbv[ct] = *(const float4*)(HbT +
          ((size_t)(b * 256) + c0 + ct * 16 + n) * 256 + j0 + quad * 4);
#pragma unroll
    for (int i = 0; i < 4; i++) {
      const bf16x8 af = *(const bf16x8*)((const char*)sEbU +
          (size_t)(i * NN + j0 + n) * 48 + (quad & 1) * 16);
      const float4 adjv = *(const float4*)(sAdj + i * NN + j0 + quad * 4);
#pragma unroll
      for (int ct = 0; ct < 4; ct++) {
        f32x4 cseed;  // per-row seed ha+hb, added exactly inside MFMA
        cseed[0] = hav[i][ct] + hbv[ct].x;
        cseed[1] = hav[i][ct] + hbv[ct].y;
        cseed[2] = hav[i][ct] + hbv[ct].z;
        cseed[3] = hav[i][ct] + hbv[ct].w;
        f32x4 acc = __builtin_amdgcn_mfma_f32_16x16x32_bf16(
            af, bfrag[ct].v, cseed, 0, 0, 0);
        outp[i][ct] = fmaf(adjv.x, fmaxf(acc[0], 0.f), outp[i][ct]);
        outp[i][ct] = fmaf(adjv.y, fmaxf(acc[1], 0.f), outp[i][ct]);
        outp[i][ct] = fmaf(adjv.z, fmaxf(acc[2], 0.f), outp[i][ct]);
        outp[i][ct] = fmaf(adjv.w, fmaxf(acc[3], 0.f), outp[i][ct]);
      }
    }
  }

  // ---- reduce across quads, store ----
#pragma unroll
  for (int i = 0; i < 4; i++)
#pragma unroll
    for (int ct = 0; ct < 4; ct++) {
      float v = outp[i][ct];
      v += __shfl_xor(v, 16);
      v += __shfl_xor(v, 32);
      if (quad == 0)
        aggH[(size_t)(r0 + i) * HID + c0 + ct * 16 + n] = v;
    }
}

// ---------------------------------------------------------------------------
// K3 (MFMA chain, packed B, 2 barriers): unchanged from R8 (proven).
// ---------------------------------------------------------------------------
#define SAGG_LD 136
#define SU_LD 264
__global__ __launch_bounds__(256) void k3_mfma(
    const float* __restrict__ h, const float* __restrict__ aggH,
    const float* __restrict__ cnt, const unsigned short* __restrict__ PW2,
    const float* __restrict__ b2, const unsigned short* __restrict__ PU1,
    const float* __restrict__ c1, const unsigned short* __restrict__ PU2,
    const float* __restrict__ c2, float* __restrict__ out) {
  __shared__ __align__(16) unsigned short sAgg[16 * SAGG_LD];
  __shared__ __align__(16) unsigned short sU[16 * SU_LD];
  const int tid = threadIdx.x;
  const int lane = tid & 63;
  const int wave = tid >> 6;
  const int ln = lane & 15;
  const int quad = lane >> 4;
  const int r0 = blockIdx.x * 16;

  {
    BF8 afr[8];
    const float4* g4 = (const float4*)aggH;
    const int abase = (r0 + ln) * 64 + quad * 2;
#pragma unroll
    for (int ks = 0; ks < 8; ks++)
      afr[ks] = make_bf8(g4[abase + ks * 8], g4[abase + ks * 8 + 1]);
    const float4 cntv = *(const float4*)(cnt + r0 + quad * 4);
#pragma unroll
    for (int t = 0; t < 2; t++) {
      const int nt = 2 * wave + t;
      const int ncol = nt * 16 + ln;
      const float bv = b2[ncol];
      f32x4 acc;
      acc[0] = cntv.x * bv; acc[1] = cntv.y * bv;
      acc[2] = cntv.z * bv; acc[3] = cntv.w * bv;
#pragma unroll
      for (int ks = 0; ks < 8; ks++) {
        const BF8 bf = *(const BF8*)(PW2 + (size_t)((nt * 8 + ks) * 64 + lane) * 8);
        acc = __builtin_amdgcn_mfma_f32_16x16x32_bf16(afr[ks].v, bf.v, acc, 0, 0, 0);
      }
#pragma unroll
      for (int r = 0; r < 4; r++)
        sAgg[(quad * 4 + r) * SAGG_LD + ncol] = f2bf(acc[r]);
    }
  }
  __syncthreads();

  {
    BF8 ah[4];
    const float4* h4 = (const float4*)h;
    const int abase = (r0 + ln) * 32 + quad * 2;
#pragma unroll
    for (int ks = 0; ks < 4; ks++)
      ah[ks] = make_bf8(h4[abase + ks * 8], h4[abase + ks * 8 + 1]);
    BF8 ag[4];
#pragma unroll
    for (int ks = 0; ks < 4; ks++)
      ag[ks] = *(const BF8*)&sAgg[ln * SAGG_LD + ks * 32 + quad * 8];
#pragma unroll
    for (int t = 0; t < 4; t++) {
      const int nt = 4 * wave + t;
      const int ncol = nt * 16 + ln;
      const float seed = c1[ncol];
      f32x4 acc;
      acc[0] = seed; acc[1] = seed; acc[2] = seed; acc[3] = seed;
#pragma unroll
      for (int ks = 0; ks < 4; ks++) {
        const BF8 bf = *(const BF8*)(PU1 + (size_t)((nt * 8 + ks) * 64 + lane) * 8);
        acc = __builtin_amdgcn_mfma_f32_16x16x32_bf16(ah[ks].v, bf.v, acc, 0, 0, 0);
      }
#pragma unroll
      for (int ks = 0; ks < 4; ks++) {
        const BF8 bf = *(const BF8*)(PU1 + (size_t)((nt * 8 + ks + 4) * 64 + lane) * 8);
        acc = __builtin_amdgcn_mfma_f32_16x16x32_bf16(ag[ks].v, bf.v, acc, 0, 0, 0);
      }
#pragma unroll
      for (int r = 0; r < 4; r++)
        sU[(quad * 4 + r) * SU_LD + ncol] = f2bf(fmaxf(acc[r], 0.f));
    }
  }
  __syncthreads();

  {
    BF8 au[8];
#pragma unroll
    for (int ks = 0; ks < 8; ks++)
      au[ks] = *(const BF8*)&sU[ln * SU_LD + ks * 32 + quad * 8];
#pragma unroll
    for (int t = 0; t < 2; t++) {
      const int nt = 2 * wave + t;
      const int ncol = nt * 16 + ln;
      const float seed = c2[ncol];
      f32x4 acc;
      acc[0] = seed; acc[1] = seed; acc[2] = seed; acc[3] = seed;
#pragma unroll
      for (int ks = 0; ks < 8; ks++) {
        const BF8 bf = *(const BF8*)(PU2 + (size_t)((nt * 8 + ks) * 64 + lane) * 8);
        acc = __builtin_amdgcn_mfma_f32_16x16x32_bf16(au[ks].v, bf.v, acc, 0, 0, 0);
      }
#pragma unroll
      for (int r = 0; r < 4; r++)
        out[(size_t)(r0 + quad * 4 + r) * NODE_DIM + ncol] = acc[r];
    }
  }
}

extern "C" void kernel_launch(void* const* d_in, const int* in_sizes, int n_in,
                              void* d_out, int out_size, void* d_ws, size_t ws_size,
                              hipStream_t stream) {
  const float* h   = (const float*)d_in[0];
  const float* adj = (const float*)d_in[1];
  const float* E   = (const float*)d_in[2];
  const float* W1  = (const float*)d_in[3];
  const float* b1  = (const float*)d_in[4];
  const float* W2  = (const float*)d_in[5];
  const float* b2  = (const float*)d_in[6];
  const float* U1  = (const float*)d_in[7];
  const float* c1  = (const float*)d_in[8];
  const float* U2  = (const float*)d_in[9];
  const float* c2  = (const float*)d_in[10];
  float* out = (float*)d_out;

  const size_t ROWS = (size_t)NB * NN;  // 2048
  float* ws   = (float*)d_ws;
  float* Ha   = ws;                      // 2048*256
  float* HbT  = ws + ROWS * HID;         // [8][256][256] transposed
  float* aggH = ws + 2 * ROWS * HID;     // 2048*256
  float* cnt  = ws + 3 * ROWS * HID;     // 2048
  unsigned short* P = (unsigned short*)(cnt + ROWS);
  unsigned short* PW1 = P;
  unsigned short* PW2 = P + PW1_SHORTS;
  unsigned short* PU1 = PW2 + PW2_SHORTS;
  unsigned short* PU2 = PU1 + PU1_SHORTS;

  kw_pack<<<100, 256, 0, stream>>>(W1, W2, U1, U2, P);
  k1_mfma<<<256, 256, 0, stream>>>(h, PW1, b1, Ha, HbT);
  k2_mfma<<<ROWS / 4, 256, 0, stream>>>(Ha, HbT, E, adj, PW1, aggH, cnt);
  k3_mfma<<<ROWS / 16, 256, 0, stream>>>(h, aggH, cnt, PW2, b2, PU1, c1, PU2, c2, out);
}

// Round 10
// 129.800 us; speedup vs baseline: 1.1135x; 1.1135x over previous
//
#include <hip/hip_runtime.h>

#define NODE_DIM 128
#define EDGE_DIM 16
#define MSG_DIM 128
#define HID 256
#define NB 8
#define NN 256

typedef short bf16x8 __attribute__((ext_vector_type(8)));
typedef float f32x4 __attribute__((ext_vector_type(4)));

__device__ __forceinline__ unsigned short f2bf(float f) {
  unsigned u = __float_as_uint(f);
  return (unsigned short)((u + 0x7FFF + ((u >> 16) & 1)) >> 16);
}
__device__ __forceinline__ unsigned pack_bf2(float lo, float hi) {
  unsigned a = __float_as_uint(lo), b = __float_as_uint(hi);
  a = (a + 0x7FFF + ((a >> 16) & 1)) >> 16;
  b = (b + 0x7FFF + ((b >> 16) & 1)) & 0xFFFF0000u;
  return a | b;
}

union BF8 { bf16x8 v; unsigned u[4]; unsigned short s[8]; };

__device__ __forceinline__ BF8 make_bf8(float4 a, float4 b) {
  BF8 r;
  r.u[0] = pack_bf2(a.x, a.y); r.u[1] = pack_bf2(a.z, a.w);
  r.u[2] = pack_bf2(b.x, b.y); r.u[3] = pack_bf2(b.z, b.w);
  return r;
}

// Packed-fragment sizes (shorts). PW1: nt 0..15, ks 0..8 (ks=8 = edge rows
// 256..271 + zero pad = k2's B-fragment). Others: ks 0..7.
#define PW1_SHORTS (16 * 9 * 64 * 8)
#define PW2_SHORTS (8 * 8 * 64 * 8)
#define PU1_SHORTS (16 * 8 * 64 * 8)
#define PU2_SHORTS (8 * 8 * 64 * 8)

// ---------------------------------------------------------------------------
// kW: repack W1/W2/U1/U2 fp32 -> bf16 B-fragment order.
// ---------------------------------------------------------------------------
__global__ __launch_bounds__(256) void kw_pack(
    const float* __restrict__ W1, const float* __restrict__ W2,
    const float* __restrict__ U1, const float* __restrict__ U2,
    unsigned short* __restrict__ P) {
  const int gl = blockIdx.x * 256 + threadIdx.x;
  const float* W; unsigned short* dst; int nt, ks, lane, N, K;
  int i = gl;
  if (i < 16 * 9 * 64) {
    W = W1; dst = P; nt = i / (9 * 64); ks = (i / 64) % 9; lane = i & 63;
    N = HID; K = 272;
  } else if ((i -= 16 * 9 * 64) < 8 * 8 * 64) {
    W = W2; dst = P + PW1_SHORTS; nt = i / (8 * 64); ks = (i / 64) % 8;
    lane = i & 63; N = MSG_DIM; K = 256;
  } else if ((i -= 8 * 8 * 64) < 16 * 8 * 64) {
    W = U1; dst = P + PW1_SHORTS + PW2_SHORTS; nt = i / (8 * 64);
    ks = (i / 64) % 8; lane = i & 63; N = HID; K = 256;
  } else if ((i -= 16 * 8 * 64) < 8 * 8 * 64) {
    W = U2; dst = P + PW1_SHORTS + PW2_SHORTS + PU1_SHORTS; nt = i / (8 * 64);
    ks = (i / 64) % 8; lane = i & 63; N = NODE_DIM; K = 256;
  } else {
    return;
  }
  const int quad = lane >> 4, ln = lane & 15;
  float v[8];
#pragma unroll
  for (int j = 0; j < 8; j++) {
    const int row = ks * 32 + quad * 8 + j;
    v[j] = (row < K) ? W[(size_t)row * N + nt * 16 + ln] : 0.f;
  }
  BF8 r;
#pragma unroll
  for (int t = 0; t < 4; t++) r.u[t] = pack_bf2(v[2 * t], v[2 * t + 1]);
  *(BF8*)(dst + (size_t)((nt * ((W == W1) ? 9 : 8) + ks) * 64 + lane) * 8) = r;
}

// ---------------------------------------------------------------------------
// K1 (MFMA, no barriers, packed B): Ha = h@W1[0:128]+b1 (row-major);
// HbS = h@W1[128:256] in k2-fragment order [b][jt][ctg][lane][4 floats]
// so both k1's store and k2's load are single coalesced 16B/lane ops.
// Grid 256 = 128 rowBlks x 2 col-halves; wave -> 2 n-tiles.
// ---------------------------------------------------------------------------
__global__ __launch_bounds__(256) void k1_mfma(
    const float* __restrict__ h, const unsigned short* __restrict__ PW1,
    const float* __restrict__ b1, float* __restrict__ Ha, float* __restrict__ HbS) {
  const int tid = threadIdx.x;
  const int lane = tid & 63;
  const int wave = tid >> 6;
  const int ln = lane & 15;
  const int quad = lane >> 4;
  const int r0 = (blockIdx.x >> 1) * 16;
  const int nbase = (blockIdx.x & 1) * 8;
  const int b = r0 >> 8;
  const int jt = (r0 & 255) >> 4;

  BF8 afr[4];
  const float4* h4 = (const float4*)h;
  const int abase = (r0 + ln) * 32 + quad * 2;
#pragma unroll
  for (int ks = 0; ks < 4; ks++)
    afr[ks] = make_bf8(h4[abase + ks * 8], h4[abase + ks * 8 + 1]);

#pragma unroll
  for (int t = 0; t < 2; t++) {
    const int nt = nbase + wave * 2 + t;  // 0..15
    const int ncol = nt * 16 + ln;
    const float seed = b1[ncol];
    f32x4 acc_a, acc_b;
    acc_a[0] = seed; acc_a[1] = seed; acc_a[2] = seed; acc_a[3] = seed;
    acc_b[0] = 0.f; acc_b[1] = 0.f; acc_b[2] = 0.f; acc_b[3] = 0.f;
#pragma unroll
    for (int ks = 0; ks < 4; ks++) {
      const BF8 bfa = *(const BF8*)(PW1 + (size_t)((nt * 9 + ks) * 64 + lane) * 8);
      const BF8 bfb = *(const BF8*)(PW1 + (size_t)((nt * 9 + ks + 4) * 64 + lane) * 8);
      acc_a = __builtin_amdgcn_mfma_f32_16x16x32_bf16(afr[ks].v, bfa.v, acc_a, 0, 0, 0);
      acc_b = __builtin_amdgcn_mfma_f32_16x16x32_bf16(afr[ks].v, bfb.v, acc_b, 0, 0, 0);
    }
#pragma unroll
    for (int r = 0; r < 4; r++)
      Ha[(size_t)(r0 + quad * 4 + r) * HID + ncol] = acc_a[r];
    // fragment-order store: one coalesced float4 per lane
    float4 hb4;
    hb4.x = acc_b[0]; hb4.y = acc_b[1]; hb4.z = acc_b[2]; hb4.w = acc_b[3];
    ((float4*)HbS)[((size_t)((b * 16 + jt) * 16 + nt)) * 64 + lane] = hb4;
  }
}

// ---------------------------------------------------------------------------
// K2 v3 (MFMA, ONE barrier, R=2 rows/block, grid 1024):
//   aggH[i,c] = sum_j adj[i,j]*relu(Ha[i,c] + Hb[j,c] + E[i,j,:]@W1c[:,c])
// E staged in A-frag order [i][jt][half][n][16B] (conflict-free 16B/lane);
// Hb read from HbS fragment-order (coalesced dwordx4, no LDS, no barriers);
// MFMA C seeded with ha+hb (exact fp32); B-frag = PW1 ks=8.
// ---------------------------------------------------------------------------
__global__ __launch_bounds__(256, 4) void k2_mfma(
    const float* __restrict__ Ha, const float* __restrict__ HbS,
    const float* __restrict__ E, const float* __restrict__ adj,
    const unsigned short* __restrict__ PW1, float* __restrict__ aggH,
    float* __restrict__ cnt) {
  __shared__ __align__(16) unsigned sEf[2 * 16 * 2 * 16 * 4];  // 16 KB
  __shared__ __align__(16) float sAdj[2 * NN];                 // 2 KB
  const int tid = threadIdx.x;
  const int lane = tid & 63;
  const int wave = tid >> 6;
  const int n = lane & 15;
  const int quad = lane >> 4;
  const int c0 = wave * 64;
  const int r0 = blockIdx.x * 2;
  const int b = r0 >> 8;

  // ---- stage E (fp32 -> bf16, A-fragment order) and adj ----
  const float4* Eb4 = (const float4*)(E + (size_t)r0 * NN * EDGE_DIM);
  for (int q = tid; q < 2 * NN * 4; q += 256) {
    const float4 v = Eb4[q];
    const int row = q >> 2;  // i*256 + jg
    const int ku = q & 3;
    const int base = (((((row >> 8) * 16 + ((row & 255) >> 4)) * 2 + (ku >> 1)) * 16)
                      + (row & 15)) * 4 + (ku & 1) * 2;
    sEf[base] = pack_bf2(v.x, v.y);
    sEf[base + 1] = pack_bf2(v.z, v.w);
  }
  for (int idx = tid; idx < 2 * NN; idx += 256)
    sAdj[idx] = adj[(size_t)r0 * NN + idx];

  // ---- B fragments from packed W1 (ks=8 = edge rows + pad) ----
  BF8 bfrag[4];
#pragma unroll
  for (int ct = 0; ct < 4; ct++) {
    const int nt = (c0 >> 4) + ct;
    bfrag[ct] = *(const BF8*)(PW1 + (size_t)((nt * 9 + 8) * 64 + lane) * 8);
  }
  float hav[2][4];
#pragma unroll
  for (int i = 0; i < 2; i++)
#pragma unroll
    for (int ct = 0; ct < 4; ct++)
      hav[i][ct] = Ha[(size_t)(r0 + i) * HID + c0 + ct * 16 + n];

  __syncthreads();  // the only barrier

  // ---- cnt: waves 0,1 reduce their adj row ----
  if (wave < 2) {
    float s = sAdj[wave * NN + lane] + sAdj[wave * NN + lane + 64] +
              sAdj[wave * NN + lane + 128] + sAdj[wave * NN + lane + 192];
    for (int d = 32; d; d >>= 1) s += __shfl_xor(s, d);
    if (lane == 0) cnt[r0 + wave] = s;
  }

  float outp[2][4];
#pragma unroll
  for (int i = 0; i < 2; i++)
#pragma unroll
    for (int ct = 0; ct < 4; ct++) outp[i][ct] = 0.f;

  // ---- barrier-free main loop over j-tiles of 16 ----
  for (int jt = 0; jt < 16; jt++) {
    const int j0 = jt * 16;
    float4 hbv[4];
#pragma unroll
    for (int ct = 0; ct < 4; ct++)
      hbv[ct] = ((const float4*)HbS)[
          ((size_t)((b * 16 + jt) * 16 + (c0 >> 4) + ct)) * 64 + lane];
#pragma unroll
    for (int i = 0; i < 2; i++) {
      const bf16x8 af = *(const bf16x8*)&sEf[
          (((i * 16 + jt) * 2 + (quad & 1)) * 16 + n) * 4];
      const float4 adjv = *(const float4*)(sAdj + i * NN + j0 + quad * 4);
#pragma unroll
      for (int ct = 0; ct < 4; ct++) {
        f32x4 cs;
        cs[0] = hav[i][ct] + hbv[ct].x;
        cs[1] = hav[i][ct] + hbv[ct].y;
        cs[2] = hav[i][ct] + hbv[ct].z;
        cs[3] = hav[i][ct] + hbv[ct].w;
        f32x4 acc = __builtin_amdgcn_mfma_f32_16x16x32_bf16(
            af, bfrag[ct].v, cs, 0, 0, 0);
        outp[i][ct] = fmaf(adjv.x, fmaxf(acc[0], 0.f), outp[i][ct]);
        outp[i][ct] = fmaf(adjv.y, fmaxf(acc[1], 0.f), outp[i][ct]);
        outp[i][ct] = fmaf(adjv.z, fmaxf(acc[2], 0.f), outp[i][ct]);
        outp[i][ct] = fmaf(adjv.w, fmaxf(acc[3], 0.f), outp[i][ct]);
      }
    }
  }

  // ---- reduce across quads, store ----
#pragma unroll
  for (int i = 0; i < 2; i++)
#pragma unroll
    for (int ct = 0; ct < 4; ct++) {
      float v = outp[i][ct];
      v += __shfl_xor(v, 16);
      v += __shfl_xor(v, 32);
      if (quad == 0)
        aggH[(size_t)(r0 + i) * HID + c0 + ct * 16 + n] = v;
    }
}

// ---------------------------------------------------------------------------
// K3 (MFMA chain, packed B, 2 barriers): unchanged from R8 (proven).
// ---------------------------------------------------------------------------
#define SAGG_LD 136
#define SU_LD 264
__global__ __launch_bounds__(256) void k3_mfma(
    const float* __restrict__ h, const float* __restrict__ aggH,
    const float* __restrict__ cnt, const unsigned short* __restrict__ PW2,
    const float* __restrict__ b2, const unsigned short* __restrict__ PU1,
    const float* __restrict__ c1, const unsigned short* __restrict__ PU2,
    const float* __restrict__ c2, float* __restrict__ out) {
  __shared__ __align__(16) unsigned short sAgg[16 * SAGG_LD];
  __shared__ __align__(16) unsigned short sU[16 * SU_LD];
  const int tid = threadIdx.x;
  const int lane = tid & 63;
  const int wave = tid >> 6;
  const int ln = lane & 15;
  const int quad = lane >> 4;
  const int r0 = blockIdx.x * 16;

  {
    BF8 afr[8];
    const float4* g4 = (const float4*)aggH;
    const int abase = (r0 + ln) * 64 + quad * 2;
#pragma unroll
    for (int ks = 0; ks < 8; ks++)
      afr[ks] = make_bf8(g4[abase + ks * 8], g4[abase + ks * 8 + 1]);
    const float4 cntv = *(const float4*)(cnt + r0 + quad * 4);
#pragma unroll
    for (int t = 0; t < 2; t++) {
      const int nt = 2 * wave + t;
      const int ncol = nt * 16 + ln;
      const float bv = b2[ncol];
      f32x4 acc;
      acc[0] = cntv.x * bv; acc[1] = cntv.y * bv;
      acc[2] = cntv.z * bv; acc[3] = cntv.w * bv;
#pragma unroll
      for (int ks = 0; ks < 8; ks++) {
        const BF8 bf = *(const BF8*)(PW2 + (size_t)((nt * 8 + ks) * 64 + lane) * 8);
        acc = __builtin_amdgcn_mfma_f32_16x16x32_bf16(afr[ks].v, bf.v, acc, 0, 0, 0);
      }
#pragma unroll
      for (int r = 0; r < 4; r++)
        sAgg[(quad * 4 + r) * SAGG_LD + ncol] = f2bf(acc[r]);
    }
  }
  __syncthreads();

  {
    BF8 ah[4];
    const float4* h4 = (const float4*)h;
    const int abase = (r0 + ln) * 32 + quad * 2;
#pragma unroll
    for (int ks = 0; ks < 4; ks++)
      ah[ks] = make_bf8(h4[abase + ks * 8], h4[abase + ks * 8 + 1]);
    BF8 ag[4];
#pragma unroll
    for (int ks = 0; ks < 4; ks++)
      ag[ks] = *(const BF8*)&sAgg[ln * SAGG_LD + ks * 32 + quad * 8];
#pragma unroll
    for (int t = 0; t < 4; t++) {
      const int nt = 4 * wave + t;
      const int ncol = nt * 16 + ln;
      const float seed = c1[ncol];
      f32x4 acc;
      acc[0] = seed; acc[1] = seed; acc[2] = seed; acc[3] = seed;
#pragma unroll
      for (int ks = 0; ks < 4; ks++) {
        const BF8 bf = *(const BF8*)(PU1 + (size_t)((nt * 8 + ks) * 64 + lane) * 8);
        acc = __builtin_amdgcn_mfma_f32_16x16x32_bf16(ah[ks].v, bf.v, acc, 0, 0, 0);
      }
#pragma unroll
      for (int ks = 0; ks < 4; ks++) {
        const BF8 bf = *(const BF8*)(PU1 + (size_t)((nt * 8 + ks + 4) * 64 + lane) * 8);
        acc = __builtin_amdgcn_mfma_f32_16x16x32_bf16(ag[ks].v, bf.v, acc, 0, 0, 0);
      }
#pragma unroll
      for (int r = 0; r < 4; r++)
        sU[(quad * 4 + r) * SU_LD + ncol] = f2bf(fmaxf(acc[r], 0.f));
    }
  }
  __syncthreads();

  {
    BF8 au[8];
#pragma unroll
    for (int ks = 0; ks < 8; ks++)
      au[ks] = *(const BF8*)&sU[ln * SU_LD + ks * 32 + quad * 8];
#pragma unroll
    for (int t = 0; t < 2; t++) {
      const int nt = 2 * wave + t;
      const int ncol = nt * 16 + ln;
      const float seed = c2[ncol];
      f32x4 acc;
      acc[0] = seed; acc[1] = seed; acc[2] = seed; acc[3] = seed;
#pragma unroll
      for (int ks = 0; ks < 8; ks++) {
        const BF8 bf = *(const BF8*)(PU2 + (size_t)((nt * 8 + ks) * 64 + lane) * 8);
        acc = __builtin_amdgcn_mfma_f32_16x16x32_bf16(au[ks].v, bf.v, acc, 0, 0, 0);
      }
#pragma unroll
      for (int r = 0; r < 4; r++)
        out[(size_t)(r0 + quad * 4 + r) * NODE_DIM + ncol] = acc[r];
    }
  }
}

extern "C" void kernel_launch(void* const* d_in, const int* in_sizes, int n_in,
                              void* d_out, int out_size, void* d_ws, size_t ws_size,
                              hipStream_t stream) {
  const float* h   = (const float*)d_in[0];
  const float* adj = (const float*)d_in[1];
  const float* E   = (const float*)d_in[2];
  const float* W1  = (const float*)d_in[3];
  const float* b1  = (const float*)d_in[4];
  const float* W2  = (const float*)d_in[5];
  const float* b2  = (const float*)d_in[6];
  const float* U1  = (const float*)d_in[7];
  const float* c1  = (const float*)d_in[8];
  const float* U2  = (const float*)d_in[9];
  const float* c2  = (const float*)d_in[10];
  float* out = (float*)d_out;

  const size_t ROWS = (size_t)NB * NN;  // 2048
  float* ws   = (float*)d_ws;
  float* Ha   = ws;                      // 2048*256
  float* HbS  = ws + ROWS * HID;         // [8][16][16][64][4] fragment-order
  float* aggH = ws + 2 * ROWS * HID;     // 2048*256
  float* cnt  = ws + 3 * ROWS * HID;     // 2048
  unsigned short* P = (unsigned short*)(cnt + ROWS);
  unsigned short* PW1 = P;
  unsigned short* PW2 = P + PW1_SHORTS;
  unsigned short* PU1 = PW2 + PW2_SHORTS;
  unsigned short* PU2 = PU1 + PU1_SHORTS;

  kw_pack<<<100, 256, 0, stream>>>(W1, W2, U1, U2, P);
  k1_mfma<<<256, 256, 0, stream>>>(h, PW1, b1, Ha, HbS);
  k2_mfma<<<ROWS / 2, 256, 0, stream>>>(Ha, HbS, E, adj, PW1, aggH, cnt);
  k3_mfma<<<ROWS / 16, 256, 0, stream>>>(h, aggH, cnt, PW2, b2, PU1, c1, PU2, c2, out);
}